// Round 3
// baseline (160.118 us; speedup 1.0000x reference)
//
#include <hip/hip_runtime.h>
#include <hip/hip_fp16.h>
#include <math.h>

#define EPS 0.05f
#define INV_EPS 20.0f
#define BIGF 1e30f

typedef short bf16x8 __attribute__((ext_vector_type(8)));
typedef float f32x4 __attribute__((ext_vector_type(4)));

__device__ __forceinline__ unsigned f2bf(float x) {
  unsigned u = __float_as_uint(x);
  return (u + 0x7fffu + ((u >> 16) & 1u)) >> 16;  // RNE f32->bf16
}
__device__ __forceinline__ unsigned pk2(float a, float b) {
  return (f2bf(a) & 0xffffu) | (f2bf(b) << 16);
}

// ---- Sinkhorn-path LDS arena (bytes). Hs and Gm alias (sequential lifetime).
#define S_HS   0        // short [128][72] = 18432  (Gram staging, bf16)
#define S_GM   0        // half  [128][130] = 33280 (Gram result; alias ok)
#define S_KR   33280    // float [48][116] = 22272  -> 55552 (Ce, then K)
#define S_DIAG 55552    // float [128]  -> 56064
#define S_IA   56064    // int   [48]   -> 56256
#define S_IB   56256    // int   [112]  -> 56704
#define S_RV   56704    // float [48]   -> 56896
#define S_CV   56896    // float [112]  -> 57344
#define S_UV   57344    // float [48]   -> 57536
#define S_VV   57536    // float [112]  -> 57984
#define S_SV   57984    // float [48]   -> 58176
#define S_TV   58176    // float [112]  -> 58624
#define S_CNT  58624    // int   [4]    -> 58640
#define S_RED  58640    // float [8]    -> 58672
#define SMEM_SZ 58688

__global__ __launch_bounds__(512)
void k_mega(const float* __restrict__ H, const int* __restrict__ ttid,
            const int* __restrict__ amask,
            const float* __restrict__ Wc, const float* __restrict__ bc,
            const float* __restrict__ Ws, const float* __restrict__ bs,
            const float* __restrict__ gate,
            float* __restrict__ dcross, float* __restrict__ cnt,
            float* __restrict__ fused)
{
  __shared__ __align__(16) char smem[SMEM_SZ];
  const int t = threadIdx.x;
  const int bid = blockIdx.x;

  if (bid < 64) {
    // ================= compact-support Sinkhorn (unchanged, verified) ======
    const int b = bid;
    short*  Hs   = (short*)(smem + S_HS);
    __half* Gm   = (__half*)(smem + S_GM);
    float*  Kr   = (float*)(smem + S_KR);
    float*  diag = (float*)(smem + S_DIAG);
    int*    ia   = (int*)(smem + S_IA);
    int*    ib   = (int*)(smem + S_IB);
    float*  rv   = (float*)(smem + S_RV);
    float*  cv   = (float*)(smem + S_CV);
    float*  uv   = (float*)(smem + S_UV);
    float*  vv   = (float*)(smem + S_VV);
    float*  Svv  = (float*)(smem + S_SV);
    float*  Tvv  = (float*)(smem + S_TV);
    int*    cnts = (int*)(smem + S_CNT);
    float*  red  = (float*)(smem + S_RED);

    const int lane = t & 63;
    const int w = t >> 6;

    // ---- Phase A: compact index lists via ballot prefix-sum ----
    int flagA = 0, flagB = 0;
    unsigned long long mA = 0, mB = 0;
    if (t < 128) {
      int a_ = amask[b*128 + t], tt_ = ttid[b*128 + t];
      flagA = (a_ == 1 && tt_ == 0);
      flagB = (a_ == 1 && tt_ == 1);
      mA = __ballot(flagA);
      mB = __ballot(flagB);
      if (lane == 0) { cnts[w] = __popcll(mA); cnts[2 + w] = __popcll(mB); }
    }
    __syncthreads();
    const int n0 = cnts[0] + cnts[1];
    const int n1 = cnts[2] + cnts[3];
    if (t < 128) {
      int offA = (w == 1) ? cnts[0] : 0;
      int offB = (w == 1) ? cnts[2] : 0;
      unsigned long long below = (1ull << lane) - 1ull;
      if (flagA) ia[offA + __popcll(mA & below)] = t;
      if (flagB) ib[offB + __popcll(mB & below)] = t;
    }

    // ---- Phase B: Gram = H_b H_b^T via bf16 MFMA ----
    const int wv = t >> 6;
    const int fm = lane & 15, fg = lane >> 4;
    f32x4 acc[8];
    #pragma unroll
    for (int ct = 0; ct < 8; ct++) {
      acc[ct][0] = 0.f; acc[ct][1] = 0.f; acc[ct][2] = 0.f; acc[ct][3] = 0.f;
    }
    const float* Hb = H + (size_t)b * (128 * 768);
    const int srow = t >> 2, sc0 = (t & 3) * 16;
    const float* src = Hb + srow * 768 + sc0;
    float4 f0 = *(const float4*)(src);
    float4 f1 = *(const float4*)(src + 4);
    float4 f2 = *(const float4*)(src + 8);
    float4 f3 = *(const float4*)(src + 12);
    for (int kc = 0; kc < 12; kc++) {
      __syncthreads();
      uint4 w0, w1;
      w0.x = pk2(f0.x, f0.y); w0.y = pk2(f0.z, f0.w);
      w0.z = pk2(f1.x, f1.y); w0.w = pk2(f1.z, f1.w);
      w1.x = pk2(f2.x, f2.y); w1.y = pk2(f2.z, f2.w);
      w1.z = pk2(f3.x, f3.y); w1.w = pk2(f3.z, f3.w);
      *(uint4*)(Hs + srow * 72 + sc0) = w0;
      *(uint4*)(Hs + srow * 72 + sc0 + 8) = w1;
      __syncthreads();
      if (kc < 11) {
        const float* s2 = Hb + srow * 768 + (kc + 1) * 64 + sc0;
        f0 = *(const float4*)(s2);
        f1 = *(const float4*)(s2 + 4);
        f2 = *(const float4*)(s2 + 8);
        f3 = *(const float4*)(s2 + 12);
      }
      #pragma unroll
      for (int ks = 0; ks < 2; ks++) {
        bf16x8 afrag = *(const bf16x8*)(Hs + (wv * 16 + fm) * 72 + ks * 32 + fg * 8);
        #pragma unroll
        for (int ct = 0; ct < 8; ct++) {
          bf16x8 bfrag = *(const bf16x8*)(Hs + (ct * 16 + fm) * 72 + ks * 32 + fg * 8);
          acc[ct] = __builtin_amdgcn_mfma_f32_16x16x32_bf16(afrag, bfrag, acc[ct], 0, 0, 0);
        }
      }
    }
    __syncthreads();
    #pragma unroll
    for (int ct = 0; ct < 8; ct++) {
      int gc = ct * 16 + fm;
      #pragma unroll
      for (int q2 = 0; q2 < 4; q2++) {
        int gr = wv * 16 + fg * 4 + q2;
        Gm[gr * 130 + gc] = __float2half(acc[ct][q2]);
      }
    }
    if ((fm >> 2) == fg) diag[wv * 16 + fm] = acc[wv][fm & 3];
    for (int e = t; e < 48 * 116; e += 512) Kr[e] = BIGF;
    __syncthreads();

    // ---- Phase C: compact Ce, shifts r/c, K transform ----
    for (int i = t >> 7; i < n0; i += 4) {
      int ra = ia[i];
      float di = diag[ra];
      for (int j = t & 127; j < n1; j += 128) {
        int cb = ib[j];
        float g = __half2float(Gm[ra * 130 + cb]);
        float d2 = fmaxf(di + diag[cb] - 2.0f * g, 1e-6f);
        Kr[i * 116 + j] = sqrtf(d2) * INV_EPS;
      }
    }
    __syncthreads();
    if (t < 192) {
      int r = t >> 2, c = t & 3;
      const float* row = Kr + r * 116 + c * 28;
      float mn = BIGF;
      #pragma unroll
      for (int g = 0; g < 7; g++) {
        float4 x = *(const float4*)(row + g * 4);
        mn = fminf(mn, fminf(fminf(x.x, x.y), fminf(x.z, x.w)));
      }
      mn = fminf(mn, __shfl_xor(mn, 1));
      mn = fminf(mn, __shfl_xor(mn, 2));
      if (c == 0) rv[r] = mn;
    }
    __syncthreads();
    if (t < 448) {
      int cl = t >> 2, rr = t & 3;
      float mn = BIGF;
      #pragma unroll
      for (int g = 0; g < 12; g++) {
        int i = rr * 12 + g;
        float v = (i < n0) ? (Kr[i * 116 + cl] - rv[i]) : BIGF;
        mn = fminf(mn, v);
      }
      mn = fminf(mn, __shfl_xor(mn, 1));
      mn = fminf(mn, __shfl_xor(mn, 2));
      if (rr == 0) cv[cl] = mn;
    }
    __syncthreads();
    for (int i = t >> 7; i < 48; i += 4) {
      float ri = rv[i];
      for (int j = t & 127; j < 112; j += 128) {
        float ce = Kr[i * 116 + j];
        Kr[i * 116 + j] = __expf(fminf(ri + cv[j] - ce, 0.f));
      }
    }
    const float inv_n0 = 1.0f / (float)n0;
    const float inv_n1 = 1.0f / (float)n1;
    if (t < 112) vv[t] = (t < n1) ? inv_n1 * __expf(-cv[t]) : 0.f;
    __syncthreads();

    // ---- Phase D: 30 scaling iterations, 2 barriers each ----
    for (int it = 0; it < 30; it++) {
      if (t < 192) {
        int r = t >> 2, c = t & 3;
        const float* row = Kr + r * 116 + c * 28;
        const float* vp = vv + c * 28;
        float s = 0.f;
        #pragma unroll
        for (int g = 0; g < 7; g++) {
          float4 k4 = *(const float4*)(row + g * 4);
          float4 v4 = *(const float4*)(vp + g * 4);
          s += k4.x * v4.x + k4.y * v4.y + k4.z * v4.z + k4.w * v4.w;
        }
        s += __shfl_xor(s, 1);
        s += __shfl_xor(s, 2);
        if (c == 0) {
          Svv[r] = s;
          uv[r] = (r < n0) ? inv_n0 * __builtin_amdgcn_rcpf(s) : 0.f;
        }
      }
      __syncthreads();
      if (t < 448) {
        int cl = t >> 2, rr = t & 3;
        float s = 0.f;
        #pragma unroll
        for (int g = 0; g < 12; g++) {
          int i = rr * 12 + g;
          s += Kr[i * 116 + cl] * uv[i];
        }
        s += __shfl_xor(s, 1);
        s += __shfl_xor(s, 2);
        if (rr == 0) {
          Tvv[cl] = s;
          vv[cl] = (cl < n1) ? inv_n1 * __builtin_amdgcn_rcpf(s) : 0.f;
        }
      }
      __syncthreads();
    }

    // ---- dual value ----
    float val = 0.f;
    if (t < 48) {
      if (t < n0) val = inv_n0 * (rv[t] - __logf(Svv[t]));
    } else if (t >= 64 && t < 176) {
      int j = t - 64;
      if (j < n1) val = inv_n1 * (cv[j] - __logf(Tvv[j]));
    }
    #pragma unroll
    for (int d = 32; d > 0; d >>= 1) val += __shfl_down(val, d);
    if (lane == 0) red[w] = val;
    __syncthreads();
    if (t == 0) {
      float s = 0.f;
      #pragma unroll
      for (int i = 0; i < 8; i++) s += red[i];
      dcross[b] = EPS * s;
    }
  } else {
    // ====== MLP path: 3 chunk-blocks per batch, partial gated dots =========
    // c=0: cls-dot over rep dims [0,768)   (just H[b,0,:], no means)
    // c=1: mean-diff dims [0,256)  -> rep dims [768,1024)
    // c=2: mean-diff dims [256,768)-> rep dims [1024,1536)
    const int q = bid - 64;
    const int b = q / 3, c = q - 3 * b;
    float* buf = (float*)smem;                 // up to 768 floats
    float* afl = (float*)(smem + 4096);        // [128]
    float* bfl = (float*)(smem + 4608);        // [128]
    float* red = (float*)(smem + 5120);        // [2]
    const float* Hb = H + (size_t)b * (128 * 768);

    int F, coloff;
    if (c == 0) {
      for (int d = t; d < 768; d += 512) buf[d] = Hb[d];   // cls
      F = 3; coloff = 0;
      __syncthreads();
    } else {
      if (t < 128) {
        int a_ = amask[b*128 + t], tt_ = ttid[b*128 + t];
        afl[t] = (a_ == 1 && tt_ == 0) ? 1.0f : 0.0f;
        bfl[t] = (a_ == 1 && tt_ == 1) ? 1.0f : 0.0f;
      }
      __syncthreads();
      if (t < 64) {
        float s = afl[t] + afl[t + 64];
        #pragma unroll
        for (int d = 32; d > 0; d >>= 1) s += __shfl_down(s, d);
        if (t == 0) red[0] = s;
      } else if (t < 128) {
        int l = t - 64;
        float s = bfl[l] + bfl[l + 64];
        #pragma unroll
        for (int d = 32; d > 0; d >>= 1) s += __shfl_down(s, d);
        if (l == 0) red[1] = s;
      }
      __syncthreads();
      const float n0 = fmaxf(red[0], 1.0f), n1 = fmaxf(red[1], 1.0f);
      if (c == 1 && t == 0) { cnt[b*2] = n0; cnt[b*2 + 1] = n1; }
      const int dbase = (c == 1) ? 0 : 256;
      const int ndim  = (c == 1) ? 256 : 512;
      if (t < ndim) {
        int d = dbase + t;
        float s0 = 0.f, s1 = 0.f;
        #pragma unroll 4
        for (int i = 0; i < 128; i++) {
          float h = Hb[i * 768 + d];
          s0 += afl[i] * h;
          s1 += bfl[i] * h;
        }
        buf[t] = s0 / n0 - s1 / n1;
      }
      F = (c == 1) ? 1 : 2; coloff = 768 + dbase;
      __syncthreads();
    }

    const int lane = t & 63, wg = t >> 6;
    float4 fr[3];
    for (int f = 0; f < F; f++)
      fr[f] = *(const float4*)(buf + f * 256 + lane * 4);
    const float gg = 1.0f / (1.0f + __expf(-gate[0]));
    for (int oo = wg; oo < 320; oo += 8) {
      const float* wrow = ((oo < 256) ? (Wc + (size_t)oo * 1536)
                                      : (Ws + (size_t)(oo - 256) * 1536)) + coloff;
      float s = 0.f;
      for (int f = 0; f < F; f++) {
        float4 w4 = *(const float4*)(wrow + f * 256 + lane * 4);
        s += fr[f].x * w4.x + fr[f].y * w4.y + fr[f].z * w4.z + fr[f].w * w4.w;
      }
      #pragma unroll
      for (int d = 32; d > 0; d >>= 1) s += __shfl_down(s, d);
      if (lane == 0) {
        if (c == 0) s += (oo < 256) ? bc[oo] : bs[oo - 256];
        float gf = (oo < 256) ? (1.0f - gg) : gg;
        atomicAdd(&fused[b * 320 + oo], s * gf);
      }
    }
  }
}

__global__ __launch_bounds__(128)
void k_final(const float* __restrict__ fused, const float* __restrict__ dcross,
             const float* __restrict__ cnt,
             const float* __restrict__ lnw, const float* __restrict__ lnb,
             const float* __restrict__ Wcls, const float* __restrict__ bcls,
             float* __restrict__ out)
{
  const int b = blockIdx.x, t = threadIdx.x;
  __shared__ float feat[321];
  __shared__ float sred[4];
  for (int i = t; i < 320; i += 128) feat[i] = fused[b * 320 + i];
  if (t == 0) {
    float n0 = cnt[b*2], n1 = cnt[b*2 + 1];
    float dsa = EPS * __logf(n0) + 0.001f;   // collapsed self-Sinkhorn
    float dsb = EPS * __logf(n1) + 0.001f;
    feat[320] = dcross[b] - 0.5f * (dsa + dsb);
  }
  __syncthreads();
  float s = 0.f;
  for (int i = t; i < 321; i += 128) s += feat[i];
  #pragma unroll
  for (int d = 32; d > 0; d >>= 1) s += __shfl_down(s, d);
  if ((t & 63) == 0) sred[t >> 6] = s;
  __syncthreads();
  const float mu = (sred[0] + sred[1]) * (1.0f / 321.0f);
  __syncthreads();
  float v = 0.f;
  for (int i = t; i < 321; i += 128) { float d2 = feat[i] - mu; v += d2 * d2; }
  #pragma unroll
  for (int d = 32; d > 0; d >>= 1) v += __shfl_down(v, d);
  if ((t & 63) == 0) sred[t >> 6] = v;
  __syncthreads();
  const float rstd = rsqrtf((sred[0] + sred[1]) * (1.0f / 321.0f) + 1e-5f);
  __syncthreads();
  float p0 = 0.f, p1 = 0.f;
  for (int i = t; i < 321; i += 128) {
    float h = (feat[i] - mu) * rstd * lnw[i] + lnb[i];
    p0 += h * Wcls[i];
    p1 += h * Wcls[321 + i];
  }
  #pragma unroll
  for (int d = 32; d > 0; d >>= 1) { p0 += __shfl_down(p0, d); p1 += __shfl_down(p1, d); }
  if ((t & 63) == 0) { sred[t >> 6] = p0; sred[2 + (t >> 6)] = p1; }
  __syncthreads();
  if (t == 0) {
    out[b * 2]     = sred[0] + sred[1] + bcls[0];
    out[b * 2 + 1] = sred[2] + sred[3] + bcls[1];
  }
}

extern "C" void kernel_launch(void* const* d_in, const int* in_sizes, int n_in,
                              void* d_out, int out_size, void* d_ws, size_t ws_size,
                              hipStream_t stream)
{
  (void)in_sizes; (void)n_in; (void)out_size; (void)ws_size;
  const float* H    = (const float*)d_in[0];
  const int*   tt   = (const int*)d_in[1];
  const int*   am   = (const int*)d_in[2];
  const float* Wc   = (const float*)d_in[3];
  const float* bc   = (const float*)d_in[4];
  const float* Ws   = (const float*)d_in[5];
  const float* bs   = (const float*)d_in[6];
  const float* gate = (const float*)d_in[7];
  const float* lnw  = (const float*)d_in[8];
  const float* lnb  = (const float*)d_in[9];
  const float* Wcls = (const float*)d_in[10];
  const float* bcls = (const float*)d_in[11];
  float* out = (float*)d_out;

  float* dcross = (float*)d_ws;        // 64
  float* cntv   = dcross + 64;         // 128
  float* fusedv = cntv + 128;          // 64*320 (atomic-accumulated)

  hipMemsetAsync(fusedv, 0, 64 * 320 * sizeof(float), stream);
  k_mega<<<dim3(256), dim3(512), 0, stream>>>(H, tt, am, Wc, bc, Ws, bs, gate,
                                              dcross, cntv, fusedv);
  k_final<<<dim3(64), dim3(128), 0, stream>>>(fusedv, dcross, cntv, lnw, lnb,
                                              Wcls, bcls, out);
}

// Round 4
// 146.028 us; speedup vs baseline: 1.0965x; 1.0965x over previous
//
#include <hip/hip_runtime.h>
#include <hip/hip_fp16.h>
#include <math.h>

#define EPS 0.05f
#define INV_EPS 20.0f
#define BIGF 1e30f

typedef short bf16x8 __attribute__((ext_vector_type(8)));
typedef float f32x4 __attribute__((ext_vector_type(4)));

__device__ __forceinline__ unsigned f2bf(float x) {
  unsigned u = __float_as_uint(x);
  return (u + 0x7fffu + ((u >> 16) & 1u)) >> 16;  // RNE f32->bf16
}
__device__ __forceinline__ unsigned pk2(float a, float b) {
  return (f2bf(a) & 0xffffu) | (f2bf(b) << 16);
}

// ---- LDS arena (bytes). Aliasing by phase lifetime:
//  Phase B: HsA/HsB (double-buffered bf16 staging)
//  Phase B end: Gm (aliases Hs region, Hs dead)
//  Phase C end: KT (aliases Gm region, Gm dead)
#define S_HSA  0        // short[128][72] = 18432
#define S_HSB  18432    //              -> 36864
#define S_GM   0        // half[128][130] = 33280 (alias)
#define S_KT   0        // float[112][52] = 23296 (alias)
#define S_KR   36864    // float[48][116] = 22272 -> 59136
#define S_DIAG 59136    // f32[128] -> 59648
#define S_IA   59648    // int[48]  -> 59840
#define S_IB   59840    // int[112] -> 60288
#define S_RV   60288    // f32[48]  -> 60480
#define S_CV   60480    // f32[112] -> 60928
#define S_UV   60928    // f32[48]  -> 61120
#define S_VV   61120    // f32[112] -> 61568
#define S_CNT  61568    // int[4]   -> 61584
#define S_RED  61584    // f32[8]   -> 61616
#define SMEM_SZ 61632

__global__ __launch_bounds__(512)
void k_mega(const float* __restrict__ H, const int* __restrict__ ttid,
            const int* __restrict__ amask,
            const float* __restrict__ Wc, const float* __restrict__ bc,
            const float* __restrict__ Ws, const float* __restrict__ bs,
            const float* __restrict__ gate,
            float* __restrict__ dcross, float* __restrict__ cnt,
            float* __restrict__ fused)
{
  __shared__ __align__(16) char smem[SMEM_SZ];
  const int t = threadIdx.x;
  const int bid = blockIdx.x;

  if (bid < 64) {
    // ================= compact-support Sinkhorn =================
    const int b = bid;
    short*  HsA  = (short*)(smem + S_HSA);
    short*  HsB  = (short*)(smem + S_HSB);
    __half* Gm   = (__half*)(smem + S_GM);
    float*  KT   = (float*)(smem + S_KT);
    float*  Kr   = (float*)(smem + S_KR);
    float*  diag = (float*)(smem + S_DIAG);
    int*    ia   = (int*)(smem + S_IA);
    int*    ib   = (int*)(smem + S_IB);
    float*  rv   = (float*)(smem + S_RV);
    float*  cv   = (float*)(smem + S_CV);
    float*  uv   = (float*)(smem + S_UV);
    float*  vv   = (float*)(smem + S_VV);
    int*    cnts = (int*)(smem + S_CNT);

    const int lane = t & 63;
    const int w = t >> 6;

    // ---- Phase A: compact index lists via ballot prefix-sum ----
    int flagA = 0, flagB = 0;
    unsigned long long mA = 0, mB = 0;
    if (t < 128) {
      int a_ = amask[b*128 + t], tt_ = ttid[b*128 + t];
      flagA = (a_ == 1 && tt_ == 0);
      flagB = (a_ == 1 && tt_ == 1);
      mA = __ballot(flagA);
      mB = __ballot(flagB);
      if (lane == 0) { cnts[w] = __popcll(mA); cnts[2 + w] = __popcll(mB); }
    }
    __syncthreads();
    const int n0 = cnts[0] + cnts[1];
    const int n1 = cnts[2] + cnts[3];
    if (t < 128) {
      int offA = (w == 1) ? cnts[0] : 0;
      int offB = (w == 1) ? cnts[2] : 0;
      unsigned long long below = (1ull << lane) - 1ull;
      if (flagA) ia[offA + __popcll(mA & below)] = t;
      if (flagB) ib[offB + __popcll(mB & below)] = t;
    }

    // ---- Phase B: Gram = H_b H_b^T, bf16 MFMA, double-buffered staging ----
    const int wv = t >> 6;
    const int fm = lane & 15, fg = lane >> 4;
    f32x4 acc[8];
    #pragma unroll
    for (int ct = 0; ct < 8; ct++) {
      acc[ct][0] = 0.f; acc[ct][1] = 0.f; acc[ct][2] = 0.f; acc[ct][3] = 0.f;
    }
    const float* Hb = H + (size_t)b * (128 * 768);
    const int srow = t >> 2, sc0 = (t & 3) * 16;
    const float* srcB = Hb + srow * 768 + sc0;
    float4 f0 = *(const float4*)(srcB);
    float4 f1 = *(const float4*)(srcB + 4);
    float4 f2 = *(const float4*)(srcB + 8);
    float4 f3 = *(const float4*)(srcB + 12);
    {   // store tile 0 -> HsA
      uint4 w0, w1;
      w0.x = pk2(f0.x, f0.y); w0.y = pk2(f0.z, f0.w);
      w0.z = pk2(f1.x, f1.y); w0.w = pk2(f1.z, f1.w);
      w1.x = pk2(f2.x, f2.y); w1.y = pk2(f2.z, f2.w);
      w1.z = pk2(f3.x, f3.y); w1.w = pk2(f3.z, f3.w);
      *(uint4*)(HsA + srow * 72 + sc0) = w0;
      *(uint4*)(HsA + srow * 72 + sc0 + 8) = w1;
    }
    {   // prefetch tile 1
      const float* s2 = srcB + 64;
      f0 = *(const float4*)(s2);
      f1 = *(const float4*)(s2 + 4);
      f2 = *(const float4*)(s2 + 8);
      f3 = *(const float4*)(s2 + 12);
    }
    for (int kc = 0; kc < 12; kc++) {
      __syncthreads();     // tile kc visible in cur; prior reads of nxt done
      short* cur = (kc & 1) ? HsB : HsA;
      short* nxt = (kc & 1) ? HsA : HsB;
      if (kc < 11) {       // store tile kc+1 into the other buffer
        uint4 w0, w1;
        w0.x = pk2(f0.x, f0.y); w0.y = pk2(f0.z, f0.w);
        w0.z = pk2(f1.x, f1.y); w0.w = pk2(f1.z, f1.w);
        w1.x = pk2(f2.x, f2.y); w1.y = pk2(f2.z, f2.w);
        w1.z = pk2(f3.x, f3.y); w1.w = pk2(f3.z, f3.w);
        *(uint4*)(nxt + srow * 72 + sc0) = w0;
        *(uint4*)(nxt + srow * 72 + sc0 + 8) = w1;
        if (kc < 10) {     // prefetch tile kc+2
          const float* s2 = srcB + (kc + 2) * 64;
          f0 = *(const float4*)(s2);
          f1 = *(const float4*)(s2 + 4);
          f2 = *(const float4*)(s2 + 8);
          f3 = *(const float4*)(s2 + 12);
        }
      }
      #pragma unroll
      for (int ks = 0; ks < 2; ks++) {
        bf16x8 afrag = *(const bf16x8*)(cur + (wv * 16 + fm) * 72 + ks * 32 + fg * 8);
        #pragma unroll
        for (int ct = 0; ct < 8; ct++) {
          bf16x8 bfrag = *(const bf16x8*)(cur + (ct * 16 + fm) * 72 + ks * 32 + fg * 8);
          acc[ct] = __builtin_amdgcn_mfma_f32_16x16x32_bf16(afrag, bfrag, acc[ct], 0, 0, 0);
        }
      }
    }
    __syncthreads();       // all MFMA reads done; Hs region now dead -> Gm
    #pragma unroll
    for (int ct = 0; ct < 8; ct++) {
      int gc = ct * 16 + fm;
      #pragma unroll
      for (int q2 = 0; q2 < 4; q2++) {
        int gr = wv * 16 + fg * 4 + q2;
        Gm[gr * 130 + gc] = __float2half(acc[ct][q2]);
      }
    }
    if ((fm >> 2) == fg) diag[wv * 16 + fm] = acc[wv][fm & 3];  // f32 diag
    for (int e = t; e < 48 * 116; e += 512) Kr[e] = BIGF;
    __syncthreads();

    // ---- Phase C: compact Ce, shifts r/c, K transform, KT build ----
    for (int i = t >> 7; i < n0; i += 4) {
      int ra = ia[i];
      float di = diag[ra];
      for (int j = t & 127; j < n1; j += 128) {
        int cb = ib[j];
        float g = __half2float(Gm[ra * 130 + cb]);
        float d2 = fmaxf(di + diag[cb] - 2.0f * g, 1e-6f);
        Kr[i * 116 + j] = sqrtf(d2) * INV_EPS;
      }
    }
    __syncthreads();
    if (t < 192) {  // r_i = min_j Ce
      int r = t >> 2, c = t & 3;
      const float* row = Kr + r * 116 + c * 28;
      float mn = BIGF;
      #pragma unroll
      for (int g = 0; g < 7; g++) {
        float4 x = *(const float4*)(row + g * 4);
        mn = fminf(mn, fminf(fminf(x.x, x.y), fminf(x.z, x.w)));
      }
      mn = fminf(mn, __shfl_xor(mn, 1));
      mn = fminf(mn, __shfl_xor(mn, 2));
      if (c == 0) rv[r] = mn;
    }
    __syncthreads();
    if (t < 448) {  // c_j = min_{i<n0} (Ce - r_i)
      int cl = t >> 2, rr = t & 3;
      float mn = BIGF;
      #pragma unroll
      for (int g = 0; g < 12; g++) {
        int i = rr * 12 + g;
        float v = (i < n0) ? (Kr[i * 116 + cl] - rv[i]) : BIGF;
        mn = fminf(mn, v);
      }
      mn = fminf(mn, __shfl_xor(mn, 1));
      mn = fminf(mn, __shfl_xor(mn, 2));
      if (rr == 0) cv[cl] = mn;
    }
    __syncthreads();
    for (int i = t >> 7; i < 48; i += 4) {  // K = exp(min(r+c-Ce,0)), in place
      float ri = rv[i];
      for (int j = t & 127; j < 112; j += 128) {
        float ce = Kr[i * 116 + j];
        Kr[i * 116 + j] = __expf(fminf(ri + cv[j] - ce, 0.f));
      }
    }
    __syncthreads();       // Gm dead -> KT
    for (int i = t >> 7; i < 48; i += 4) {  // col-major copy for v-step
      int j = t & 127;
      if (j < 112) KT[j * 52 + i] = Kr[i * 116 + j];
    }
    const float inv_n0 = 1.0f / (float)n0;
    const float inv_n1 = 1.0f / (float)n1;
    if (t < 112) vv[t] = (t < n1) ? inv_n1 * __expf(-cv[t]) : 0.f;
    __syncthreads();       // LAST barrier; waves 1-7 exit after this

    // ---- Phase D: single-wave, barrier-free 30 scaling iterations ----
    if (t < 64) {
      const int l = t;
      const int r48 = (l < 48) ? l : 47;           // clamp (masked later)
      const float a_l = (l < n0) ? inv_n0 : 0.f;
      const int j2ok = (l + 64 < 112);
      const int c2 = j2ok ? (l + 64) : l;          // clamp (masked later)
      const float b1w = (l < n1) ? inv_n1 : 0.f;
      const float b2w = (j2ok && c2 < n1) ? inv_n1 : 0.f;
      const float* Krow = Kr + r48 * 116;
      const float* Kc1p = KT + l * 52;
      const float* Kc2p = KT + c2 * 52;
      float Sl = 1.f, Tc1 = 1.f, Tc2 = 1.f;
      for (int it = 0; it < 30; it++) {
        // u-step: lane l = row l
        float a0 = 0.f, a1 = 0.f, a2 = 0.f, a3 = 0.f;
        #pragma unroll
        for (int g = 0; g < 28; g++) {
          float4 k4 = *(const float4*)(Krow + 4 * g);
          float4 v4 = *(const float4*)(vv + 4 * g);  // broadcast
          a0 += k4.x * v4.x; a1 += k4.y * v4.y;
          a2 += k4.z * v4.z; a3 += k4.w * v4.w;
        }
        float S = (a0 + a1) + (a2 + a3);
        Sl = S;
        float ul = a_l * __builtin_amdgcn_rcpf(S);
        if (l < 48) uv[l] = ul;
        __asm__ volatile("s_waitcnt lgkmcnt(0)" ::: "memory");
        // v-step: lane l = cols l and l+64
        float p0 = 0.f, p1 = 0.f, q0 = 0.f, q1 = 0.f;
        #pragma unroll
        for (int g = 0; g < 12; g++) {
          float4 u4 = *(const float4*)(uv + 4 * g);  // broadcast
          float4 ka = *(const float4*)(Kc1p + 4 * g);
          float4 kb = *(const float4*)(Kc2p + 4 * g);
          p0 += ka.x * u4.x + ka.z * u4.z; p1 += ka.y * u4.y + ka.w * u4.w;
          q0 += kb.x * u4.x + kb.z * u4.z; q1 += kb.y * u4.y + kb.w * u4.w;
        }
        float T1 = p0 + p1, T2 = q0 + q1;
        Tc1 = T1; Tc2 = T2;
        vv[l] = b1w * __builtin_amdgcn_rcpf(T1);
        if (j2ok) vv[c2] = b2w * __builtin_amdgcn_rcpf(T2);
        __asm__ volatile("s_waitcnt lgkmcnt(0)" ::: "memory");
      }
      // dual value, 64-lane butterfly
      float val = (l < n0) ? inv_n0 * (rv[l] - __logf(Sl)) : 0.f;
      if (l < n1) val += inv_n1 * (cv[l] - __logf(Tc1));
      if (j2ok && c2 < n1) val += inv_n1 * (cv[c2] - __logf(Tc2));
      #pragma unroll
      for (int d = 1; d < 64; d <<= 1) val += __shfl_xor(val, d);
      if (l == 0) dcross[b] = EPS * val;
    }
  } else {
    // ================= rep / MLP path (round-2 structure) =================
    const int b = bid - 64;
    float* repv = (float*)smem;               // [1536]
    float* afl  = (float*)(smem + 8192);      // [128]
    float* bfl  = (float*)(smem + 8704);      // [128]
    float* red  = (float*)(smem + 9216);      // scratch

    if (t < 128) {
      int a_ = amask[b*128 + t], tt_ = ttid[b*128 + t];
      afl[t] = (a_ == 1 && tt_ == 0) ? 1.0f : 0.0f;
      bfl[t] = (a_ == 1 && tt_ == 1) ? 1.0f : 0.0f;
    }
    __syncthreads();
    if (t < 64) {
      float s = afl[t] + afl[t + 64];
      #pragma unroll
      for (int d = 32; d > 0; d >>= 1) s += __shfl_down(s, d);
      if (t == 0) red[0] = s;
    } else if (t < 128) {
      int l = t - 64;
      float s = bfl[l] + bfl[l + 64];
      #pragma unroll
      for (int d = 32; d > 0; d >>= 1) s += __shfl_down(s, d);
      if (l == 0) red[1] = s;
    }
    __syncthreads();
    const float n0 = fmaxf(red[0], 1.0f), n1 = fmaxf(red[1], 1.0f);
    if (t == 0) { cnt[b*2] = n0; cnt[b*2 + 1] = n1; }

    const float* Hb = H + (size_t)b * (128 * 768);
    for (int d = t; d < 768; d += 512) {
      float s0 = 0.f, s1 = 0.f;
      #pragma unroll 4
      for (int i = 0; i < 128; i++) {
        float h = Hb[i * 768 + d];
        s0 += afl[i] * h;
        s1 += bfl[i] * h;
      }
      repv[768 + d] = s0 / n0 - s1 / n1;
      repv[d] = Hb[d];  // cls
    }
    __syncthreads();

    const int klane = t & 63, og = t >> 6;
    float4 rr[6];
    #pragma unroll
    for (int c4 = 0; c4 < 6; c4++)
      rr[c4] = *(const float4*)(repv + c4 * 256 + klane * 4);
    const float gg = 1.0f / (1.0f + __expf(-gate[0]));
    for (int oo = og; oo < 320; oo += 8) {
      const float* wrow = (oo < 256) ? (Wc + (size_t)oo * 1536)
                                     : (Ws + (size_t)(oo - 256) * 1536);
      float s = 0.f;
      #pragma unroll
      for (int c4 = 0; c4 < 6; c4++) {
        float4 w4 = *(const float4*)(wrow + c4 * 256 + klane * 4);
        s += rr[c4].x * w4.x + rr[c4].y * w4.y + rr[c4].z * w4.z + rr[c4].w * w4.w;
      }
      #pragma unroll
      for (int d = 32; d > 0; d >>= 1) s += __shfl_down(s, d);
      if (klane == 0) {
        float bias = (oo < 256) ? bc[oo] : bs[oo - 256];
        fused[b * 320 + oo] = (s + bias) * ((oo < 256) ? (1.0f - gg) : gg);
      }
    }
  }
}

__global__ __launch_bounds__(128)
void k_final(const float* __restrict__ fused, const float* __restrict__ dcross,
             const float* __restrict__ cnt,
             const float* __restrict__ lnw, const float* __restrict__ lnb,
             const float* __restrict__ Wcls, const float* __restrict__ bcls,
             float* __restrict__ out)
{
  const int b = blockIdx.x, t = threadIdx.x;
  __shared__ float feat[321];
  __shared__ float sred[4];
  for (int i = t; i < 320; i += 128) feat[i] = fused[b * 320 + i];
  if (t == 0) {
    float n0 = cnt[b*2], n1 = cnt[b*2 + 1];
    float dsa = EPS * __logf(n0) + 0.001f;   // collapsed self-Sinkhorn
    float dsb = EPS * __logf(n1) + 0.001f;
    feat[320] = dcross[b] - 0.5f * (dsa + dsb);
  }
  __syncthreads();
  float s = 0.f;
  for (int i = t; i < 321; i += 128) s += feat[i];
  #pragma unroll
  for (int d = 32; d > 0; d >>= 1) s += __shfl_down(s, d);
  if ((t & 63) == 0) sred[t >> 6] = s;
  __syncthreads();
  const float mu = (sred[0] + sred[1]) * (1.0f / 321.0f);
  __syncthreads();
  float v = 0.f;
  for (int i = t; i < 321; i += 128) { float d2 = feat[i] - mu; v += d2 * d2; }
  #pragma unroll
  for (int d = 32; d > 0; d >>= 1) v += __shfl_down(v, d);
  if ((t & 63) == 0) sred[t >> 6] = v;
  __syncthreads();
  const float rstd = rsqrtf((sred[0] + sred[1]) * (1.0f / 321.0f) + 1e-5f);
  __syncthreads();
  float p0 = 0.f, p1 = 0.f;
  for (int i = t; i < 321; i += 128) {
    float h = (feat[i] - mu) * rstd * lnw[i] + lnb[i];
    p0 += h * Wcls[i];
    p1 += h * Wcls[321 + i];
  }
  #pragma unroll
  for (int d = 32; d > 0; d >>= 1) { p0 += __shfl_down(p0, d); p1 += __shfl_down(p1, d); }
  if ((t & 63) == 0) { sred[t >> 6] = p0; sred[2 + (t >> 6)] = p1; }
  __syncthreads();
  if (t == 0) {
    out[b * 2]     = sred[0] + sred[1] + bcls[0];
    out[b * 2 + 1] = sred[2] + sred[3] + bcls[1];
  }
}

extern "C" void kernel_launch(void* const* d_in, const int* in_sizes, int n_in,
                              void* d_out, int out_size, void* d_ws, size_t ws_size,
                              hipStream_t stream)
{
  (void)in_sizes; (void)n_in; (void)out_size; (void)ws_size;
  const float* H    = (const float*)d_in[0];
  const int*   tt   = (const int*)d_in[1];
  const int*   am   = (const int*)d_in[2];
  const float* Wc   = (const float*)d_in[3];
  const float* bc   = (const float*)d_in[4];
  const float* Ws   = (const float*)d_in[5];
  const float* bs   = (const float*)d_in[6];
  const float* gate = (const float*)d_in[7];
  const float* lnw  = (const float*)d_in[8];
  const float* lnb  = (const float*)d_in[9];
  const float* Wcls = (const float*)d_in[10];
  const float* bcls = (const float*)d_in[11];
  float* out = (float*)d_out;

  float* dcross = (float*)d_ws;        // 64
  float* cntv   = dcross + 64;         // 128
  float* fusedv = cntv + 128;          // 64*320

  k_mega<<<dim3(128), dim3(512), 0, stream>>>(H, tt, am, Wc, bc, Ws, bs, gate,
                                              dcross, cntv, fusedv);
  k_final<<<dim3(64), dim3(128), 0, stream>>>(fusedv, dcross, cntv, lnw, lnb,
                                              Wcls, bcls, out);
}